// Round 2
// baseline (365.309 us; speedup 1.0000x reference)
//
#include <hip/hip_runtime.h>

#define D 128

typedef int v2i __attribute__((ext_vector_type(2)));
typedef int v4i __attribute__((ext_vector_type(4)));

// ---------- bf16 helpers (raw ushort representation) ----------
__device__ __forceinline__ float bf2f(unsigned short u) {
    union { unsigned int i; float f; } v;
    v.i = ((unsigned int)u) << 16;
    return v.f;
}
__device__ __forceinline__ unsigned short f2bf(float f) {
    union { float f; unsigned int i; } v;
    v.f = f;
    unsigned int x = v.i;
    unsigned int round_bit = (x >> 16) & 1u;   // round-to-nearest-even
    x += 0x7fffu + round_bit;
    return (unsigned short)(x >> 16);
}

__device__ __forceinline__ int idx_at(const void* p, long long i, bool i64) {
    return i64 ? (int)((const long long*)p)[i] : ((const int*)p)[i];
}

// ---------- init: zero cnt (grid-stride) + layout probe flags (block 0) ----------
__global__ void init_all(int* __restrict__ cnt, int n_concat,
                         const int* __restrict__ et_i32,
                         const unsigned short* __restrict__ emb_u16,
                         int* __restrict__ flags) {
    int i = blockIdx.x * blockDim.x + threadIdx.x;
    for (; i < n_concat; i += gridDim.x * blockDim.x) cnt[i] = 0;

    if (blockIdx.x == 0 && threadIdx.x < 64) {
        int lane = threadIdx.x;                // 0..63
        int v = et_i32[2 * lane + 1];
        unsigned long long b_i64 = __ballot(v != 0);

        unsigned short a = emb_u16[2 * lane];
        unsigned short c = emb_u16[2 * lane + 1];
        int e1 = (a >> 7) & 0xFF;
        int e2 = (c >> 7) & 0xFF;
        unsigned long long b_f32 = __ballot(e1 > 140 || e2 > 140);

        if (lane == 0) {
            flags[0] = (b_i64 == 0ULL) ? 1 : 0;   // 1 => indices are int64
            flags[1] = (b_f32 != 0ULL) ? 1 : 0;   // 1 => floats are fp32
        }
    }
}

// ---------- merged histogram (entity heads ++ user rows), 2 elems/thread ----------
// Records {dst, rank} so the scatter needs no atomics.
__global__ void hist_all(const void* __restrict__ ei, const void* __restrict__ rows,
                         int* __restrict__ cnt, int2* __restrict__ dr,
                         const int* __restrict__ flags,
                         int n_edges, int nnz, int n_entities) {
    long long base = 2ll * ((long long)blockIdx.x * blockDim.x + threadIdx.x);
    bool i64 = flags[0] != 0;
    long long n_total = (long long)n_edges + nnz;
    #pragma unroll
    for (int u = 0; u < 2; ++u) {
        long long i = base + u;
        if (i >= n_total) break;
        int dst;
        if (i < n_edges) {
            dst = idx_at(ei, i, i64);
        } else {
            dst = n_entities + idx_at(rows, i - n_edges, i64);
        }
        int r = atomicAdd(&cnt[dst], 1);
        v2i p; p.x = dst; p.y = r;
        __builtin_nontemporal_store(p, (v2i*)dr + i);
    }
}

// ---------- hierarchical exclusive scan (3 phases, 256-wide tiles) ----------
__device__ __forceinline__ int block_scan_excl_256(int v, int* total) {
    __shared__ int tmp[256];
    int tid = threadIdx.x;
    tmp[tid] = v;
    __syncthreads();
    #pragma unroll
    for (int ofs = 1; ofs < 256; ofs <<= 1) {
        int t = (tid >= ofs) ? tmp[tid - ofs] : 0;
        __syncthreads();
        tmp[tid] += t;
        __syncthreads();
    }
    int incl = tmp[tid];
    *total = tmp[255];
    __syncthreads();                           // safe for reuse
    return incl - v;
}

__global__ void scan_p1(const int* __restrict__ cnt, int* __restrict__ bsums, int n) {
    int i = blockIdx.x * 256 + threadIdx.x;
    int v = (i < n) ? cnt[i] : 0;
    int total;
    block_scan_excl_256(v, &total);
    if (threadIdx.x == 0) bsums[blockIdx.x] = total;
}

__global__ void scan_p2(int* __restrict__ bsums, int nb) {
    int tid = threadIdx.x;
    int chunk = (nb + 255) / 256;
    int beg = tid * chunk;
    int end = min(beg + chunk, nb);
    int s = 0;
    for (int i = beg; i < end; ++i) s += bsums[i];
    int total;
    int run = block_scan_excl_256(s, &total);
    for (int i = beg; i < end; ++i) {
        int c = bsums[i];
        bsums[i] = run;
        run += c;
    }
}

__global__ void scan_p3(int* __restrict__ cnt, const int* __restrict__ bsums,
                        int* __restrict__ off, int n) {
    int i = blockIdx.x * 256 + threadIdx.x;
    int v = (i < n) ? cnt[i] : 0;
    int total;
    int excl = block_scan_excl_256(v, &total);
    int base = bsums[blockIdx.x];
    if (i < n) {
        off[i] = base + excl;
        cnt[i] = 0;                            // reset -> reuse as scatter cursor (fallback path)
        if (i == n - 1) off[n] = base + excl + v;
    }
}

// ---------- rank-based scatter: no atomics, 2 elems/thread for MLP ----------
__global__ void scatter_rank(const void* __restrict__ ei, const void* __restrict__ et,
                             const void* __restrict__ cols, const void* __restrict__ vals,
                             const int* __restrict__ off, const int2* __restrict__ dr,
                             int2* __restrict__ pairs, const int* __restrict__ flags,
                             int n_edges, int nnz) {
    long long base = 2ll * ((long long)blockIdx.x * blockDim.x + threadIdx.x);
    bool i64 = flags[0] != 0;
    bool f32 = flags[1] != 0;
    long long n_total = (long long)n_edges + nnz;

    // issue both dr loads + payload loads first, then both dependent stores
    int2 d[2]; int2 p[2]; int valid = 0;
    #pragma unroll
    for (int u = 0; u < 2; ++u) {
        long long i = base + u;
        if (i >= n_total) break;
        valid = u + 1;
        v2i dd = __builtin_nontemporal_load((const v2i*)dr + i);
        d[u].x = dd.x; d[u].y = dd.y;
        if (i < n_edges) {
            p[u].x = idx_at(ei, (long long)n_edges + i, i64);
            p[u].y = idx_at(et, i, i64) - 1;
        } else {
            long long k = i - n_edges;
            p[u].x = idx_at(cols, k, i64);
            float v = f32 ? ((const float*)vals)[k] : bf2f(((const unsigned short*)vals)[k]);
            p[u].y = __float_as_int(v);
        }
    }
    #pragma unroll
    for (int u = 0; u < 2; ++u) {
        if (u < valid) pairs[off[d[u].x] + d[u].y] = p[u];
    }
}

// ---------- fallback scatter with atomic cursors (ws too small for dr) ----------
__global__ void scatter_all(const void* __restrict__ ei, const void* __restrict__ et,
                            const void* __restrict__ rows, const void* __restrict__ cols,
                            const void* __restrict__ vals,
                            const int* __restrict__ off, int* __restrict__ cur,
                            int2* __restrict__ pairs, const int* __restrict__ flags,
                            int n_edges, int nnz, int n_entities) {
    long long i = (long long)blockIdx.x * blockDim.x + threadIdx.x;
    bool i64 = flags[0] != 0;
    if (i < n_edges) {
        int head = idx_at(ei, i, i64);
        int tail = idx_at(ei, (long long)n_edges + i, i64);
        int rel  = idx_at(et, i, i64) - 1;
        int pos = off[head] + atomicAdd(&cur[head], 1);
        int2 p; p.x = tail; p.y = rel;
        pairs[pos] = p;
    } else if (i < (long long)n_edges + nnz) {
        long long k = i - n_edges;
        bool f32 = flags[1] != 0;
        int rr = n_entities + idx_at(rows, k, i64);
        int c = idx_at(cols, k, i64);
        float v = f32 ? ((const float*)vals)[k] : bf2f(((const unsigned short*)vals)[k]);
        int pos = off[rr] + atomicAdd(&cur[rr], 1);
        int2 p; p.x = c; p.y = __float_as_int(v);
        pairs[pos] = p;
    }
}

// ---------- unpack 8 bf16 (uint4) -> 8 floats ----------
__device__ __forceinline__ void unpack8(uint4 q, float* e) {
    e[0] = bf2f((unsigned short)(q.x & 0xFFFFu)); e[1] = bf2f((unsigned short)(q.x >> 16));
    e[2] = bf2f((unsigned short)(q.y & 0xFFFFu)); e[3] = bf2f((unsigned short)(q.y >> 16));
    e[4] = bf2f((unsigned short)(q.z & 0xFFFFu)); e[5] = bf2f((unsigned short)(q.z >> 16));
    e[6] = bf2f((unsigned short)(q.w & 0xFFFFu)); e[7] = bf2f((unsigned short)(q.w >> 16));
}

// ---------- merged aggregate: one wave per output row, 16-lane groups ----------
// Streaming traffic (pairs reads, output stores) is non-temporal so the
// L2 keeps emb rows (re-read ~16x across the kernel) instead.
__global__ void agg_all(const void* __restrict__ emb, const void* __restrict__ weight,
                        const int* __restrict__ off, const int2* __restrict__ pairs,
                        void* __restrict__ out, const int* __restrict__ flags,
                        int n_entities, int n_total) {
    int gid = blockIdx.x * blockDim.x + threadIdx.x;
    int w = gid >> 6;
    int lane = gid & 63;
    if (w >= n_total) return;
    bool f32 = flags[1] != 0;
    bool isU = (w >= n_entities);
    int m = lane & 15;
    int g = lane >> 4;
    int beg = off[w], end = off[w + 1];
    int n = end - beg;

    float acc[8];
    #pragma unroll
    for (int i = 0; i < 8; ++i) acc[i] = 0.f;

    if (f32) {
        const float4* embq = (const float4*)emb;        // 32 float4 per row
        int nn = min(n, 64);
        int px = 0, py = 0;
        if (lane < nn) {
            v2i t = __builtin_nontemporal_load((const v2i*)pairs + beg + lane);
            px = t.x; py = t.y;
        }
        int TM = (nn + 3) >> 2;
        if (isU) {
            for (int t = 0; t < TM; ++t) {
                int jl = 4 * t + g;                      // <= 63 always
                int sx = __shfl(px, jl, 64);
                float v = __int_as_float(__shfl(py, jl, 64));  // 0.0f for jl >= nn
                const float4* rp = embq + (size_t)sx * 32 + m * 2;
                float4 a = rp[0], b = rp[1];
                acc[0] += v * a.x; acc[1] += v * a.y; acc[2] += v * a.z; acc[3] += v * a.w;
                acc[4] += v * b.x; acc[5] += v * b.y; acc[6] += v * b.z; acc[7] += v * b.w;
            }
            for (int j = beg + 64 + g; j < end; j += 4) {   // rare long-row tail
                int2 p = pairs[j];
                float v = __int_as_float(p.y);
                const float4* rp = embq + (size_t)p.x * 32 + m * 2;
                float4 a = rp[0], b = rp[1];
                acc[0] += v * a.x; acc[1] += v * a.y; acc[2] += v * a.z; acc[3] += v * a.w;
                acc[4] += v * b.x; acc[5] += v * b.y; acc[6] += v * b.z; acc[7] += v * b.w;
            }
        } else {
            const float4* wq = (const float4*)weight;
            for (int t = 0; t < TM; ++t) {
                int jl = 4 * t + g;
                int sx = __shfl(px, jl, 64);
                int sy = __shfl(py, jl, 64);             // 0 for jl >= nn (weight row 0, safe)
                const float4* rp = embq + (size_t)sx * 32 + m * 2;
                const float4* wp = wq   + (size_t)sy * 32 + m * 2;
                float4 a = rp[0], b = rp[1], wa = wp[0], wb = wp[1];
                if (jl < nn) {
                    acc[0] += a.x * wa.x; acc[1] += a.y * wa.y; acc[2] += a.z * wa.z; acc[3] += a.w * wa.w;
                    acc[4] += b.x * wb.x; acc[5] += b.y * wb.y; acc[6] += b.z * wb.z; acc[7] += b.w * wb.w;
                }
            }
            for (int j = beg + 64 + g; j < end; j += 4) {   // rare long-row tail
                int2 p = pairs[j];
                const float4* rp = embq + (size_t)p.x * 32 + m * 2;
                const float4* wp = wq   + (size_t)p.y * 32 + m * 2;
                float4 a = rp[0], b = rp[1], wa = wp[0], wb = wp[1];
                acc[0] += a.x * wa.x; acc[1] += a.y * wa.y; acc[2] += a.z * wa.z; acc[3] += a.w * wa.w;
                acc[4] += b.x * wb.x; acc[5] += b.y * wb.y; acc[6] += b.z * wb.z; acc[7] += b.w * wb.w;
            }
        }
    } else {
        const uint4* embq = (const uint4*)emb;          // row stride 16 uint4
        if (isU) {
            for (int j = beg + g; j < end; j += 4) {
                v2i t = __builtin_nontemporal_load((const v2i*)pairs + j);
                int2 p; p.x = t.x; p.y = t.y;
                uint4 q = embq[(size_t)p.x * 16 + m];
                float v = __int_as_float(p.y);
                float e[8]; unpack8(q, e);
                #pragma unroll
                for (int i = 0; i < 8; ++i) acc[i] += v * e[i];
            }
        } else {
            const uint4* wq = (const uint4*)weight;
            for (int j = beg + g; j < end; j += 4) {
                v2i t = __builtin_nontemporal_load((const v2i*)pairs + j);
                int2 p; p.x = t.x; p.y = t.y;
                uint4 q  = embq[(size_t)p.x * 16 + m];
                uint4 qw = wq[(size_t)p.y * 16 + m];
                float e[8], wv[8]; unpack8(q, e); unpack8(qw, wv);
                #pragma unroll
                for (int i = 0; i < 8; ++i) acc[i] += e[i] * wv[i];
            }
        }
    }

    // sum the 4 pair-groups
    #pragma unroll
    for (int i = 0; i < 8; ++i) {
        acc[i] += __shfl_xor(acc[i], 16, 64);
        acc[i] += __shfl_xor(acc[i], 32, 64);
    }

    if (!isU) {
        float rcp = 1.0f / fmaxf((float)(end - beg), 1.0f);
        #pragma unroll
        for (int i = 0; i < 8; ++i) acc[i] *= rcp;
    }

    if (g == 0) {                               // lanes 0..15 store the row (non-temporal)
        if (!f32) {
            v4i o;
            o.x = (int)((unsigned int)f2bf(acc[0]) | ((unsigned int)f2bf(acc[1]) << 16));
            o.y = (int)((unsigned int)f2bf(acc[2]) | ((unsigned int)f2bf(acc[3]) << 16));
            o.z = (int)((unsigned int)f2bf(acc[4]) | ((unsigned int)f2bf(acc[5]) << 16));
            o.w = (int)((unsigned int)f2bf(acc[6]) | ((unsigned int)f2bf(acc[7]) << 16));
            __builtin_nontemporal_store(o, (v4i*)out + (size_t)w * 8 + m);
        } else {
            v4i* rp = (v4i*)((float*)out + (size_t)w * D);
            v4i a, b;
            a.x = __float_as_int(acc[0]); a.y = __float_as_int(acc[1]);
            a.z = __float_as_int(acc[2]); a.w = __float_as_int(acc[3]);
            b.x = __float_as_int(acc[4]); b.y = __float_as_int(acc[5]);
            b.z = __float_as_int(acc[6]); b.w = __float_as_int(acc[7]);
            __builtin_nontemporal_store(a, rp + m * 2);
            __builtin_nontemporal_store(b, rp + m * 2 + 1);
        }
    }
}

extern "C" void kernel_launch(void* const* d_in, const int* in_sizes, int n_in,
                              void* d_out, int out_size, void* d_ws, size_t ws_size,
                              hipStream_t stream) {
    const void* emb  = d_in[0];   // [n_entities][D] bf16 or fp32
    const void* ei   = d_in[1];   // [2][n_edges]    int32 or int64
    const void* et   = d_in[2];   // [n_edges]
    const void* rows = d_in[3];   // [nnz]
    const void* cols = d_in[4];   // [nnz]
    const void* vals = d_in[5];   // [nnz] bf16 or fp32

    // weight = last input with >=256 elements (robust to scalar presence)
    const void* weight = d_in[n_in - 1];
    for (int i = n_in - 1; i >= 5; --i) {
        if (in_sizes[i] >= 256) { weight = d_in[i]; break; }
    }

    int n_entities = in_sizes[0] / D;
    int n_edges    = in_sizes[2];
    int nnz        = in_sizes[5];
    int n_users    = out_size / D - n_entities;

    int n_concat = n_entities + n_users;       // concatenated row space
    int nb = (n_concat + 255) / 256;           // scan tiles
    long long n_pairs = (long long)n_edges + nnz;

    // ws layout:
    //   [pairs: n_pairs int2][dr: n_pairs int2 (optional)][off: n_concat+1]
    //   [cnt: n_concat][bsums: nb][flags: 2]
    size_t fixed = (size_t)(n_concat + 1 + n_concat + nb + 2) * sizeof(int);
    bool use_rank = ws_size >= (size_t)n_pairs * sizeof(int2) * 2 + fixed + 256;

    char* p = (char*)d_ws;
    int2* pairs = (int2*)p;                      p += (size_t)n_pairs * sizeof(int2);
    int2* dr = nullptr;
    if (use_rank) { dr = (int2*)p;               p += (size_t)n_pairs * sizeof(int2); }
    int*  off   = (int*)p;                       p += (size_t)(n_concat + 1) * sizeof(int);
    int*  cnt   = (int*)p;                       p += (size_t)n_concat * sizeof(int);
    int*  bsums = (int*)p;                       p += (size_t)nb * sizeof(int);
    int*  flags = (int*)p;

    const int tpb = 256;

    // init: zero cnt + dtype probes (replaces memset + detect dispatches)
    init_all<<<nb, tpb, 0, stream>>>(cnt, n_concat, (const int*)et,
                                     (const unsigned short*)emb, flags);

    if (use_rank) {
        // merged histogram + rank record, 2 elems/thread
        long long nt2 = (n_pairs + 1) / 2;
        hist_all<<<(int)((nt2 + tpb - 1) / tpb), tpb, 0, stream>>>(
            ei, rows, cnt, dr, flags, n_edges, nnz, n_entities);
    } else {
        hist_all<<<(int)(((n_pairs + 1) / 2 + tpb - 1) / tpb), tpb, 0, stream>>>(
            ei, rows, cnt, dr, flags, n_edges, nnz, n_entities);
    }

    // hierarchical exclusive scan (also zeroes cnt for cursor fallback)
    scan_p1<<<nb, 256, 0, stream>>>(cnt, bsums, n_concat);
    scan_p2<<<1, 256, 0, stream>>>(bsums, nb);
    scan_p3<<<nb, 256, 0, stream>>>(cnt, bsums, off, n_concat);

    // scatter: atomic-free when ranks were recorded
    if (use_rank) {
        long long nt2 = (n_pairs + 1) / 2;
        scatter_rank<<<(int)((nt2 + tpb - 1) / tpb), tpb, 0, stream>>>(
            ei, et, cols, vals, off, dr, pairs, flags, n_edges, nnz);
    } else {
        scatter_all<<<(int)((n_pairs + tpb - 1) / tpb), tpb, 0, stream>>>(
            ei, et, rows, cols, vals, off, cnt, pairs, flags, n_edges, nnz, n_entities);
    }

    // merged gather-aggregate: one wave per output row
    {
        long long threads = (long long)n_concat * 64;
        agg_all<<<(int)((threads + tpb - 1) / tpb), tpb, 0, stream>>>(
            emb, weight, off, pairs, d_out, flags, n_entities, n_concat);
    }
}

// Round 3
// 353.594 us; speedup vs baseline: 1.0331x; 1.0331x over previous
//
#include <hip/hip_runtime.h>

#define D 128

typedef int v2i __attribute__((ext_vector_type(2)));
typedef int v4i __attribute__((ext_vector_type(4)));

// ---------- bf16 helpers (raw ushort representation) ----------
__device__ __forceinline__ float bf2f(unsigned short u) {
    union { unsigned int i; float f; } v;
    v.i = ((unsigned int)u) << 16;
    return v.f;
}
__device__ __forceinline__ unsigned short f2bf(float f) {
    union { float f; unsigned int i; } v;
    v.f = f;
    unsigned int x = v.i;
    unsigned int round_bit = (x >> 16) & 1u;   // round-to-nearest-even
    x += 0x7fffu + round_bit;
    return (unsigned short)(x >> 16);
}

__device__ __forceinline__ int idx_at(const void* p, long long i, bool i64) {
    return i64 ? (int)((const long long*)p)[i] : ((const int*)p)[i];
}

// ---------- init: zero cnt (grid-stride) + layout probe flags (block 0) ----------
__global__ void init_all(int* __restrict__ cnt, int n_concat,
                         const int* __restrict__ et_i32,
                         const unsigned short* __restrict__ emb_u16,
                         int* __restrict__ flags) {
    int i = blockIdx.x * blockDim.x + threadIdx.x;
    for (; i < n_concat; i += gridDim.x * blockDim.x) cnt[i] = 0;

    if (blockIdx.x == 0 && threadIdx.x < 64) {
        int lane = threadIdx.x;                // 0..63
        int v = et_i32[2 * lane + 1];
        unsigned long long b_i64 = __ballot(v != 0);

        unsigned short a = emb_u16[2 * lane];
        unsigned short c = emb_u16[2 * lane + 1];
        int e1 = (a >> 7) & 0xFF;
        int e2 = (c >> 7) & 0xFF;
        unsigned long long b_f32 = __ballot(e1 > 140 || e2 > 140);

        if (lane == 0) {
            flags[0] = (b_i64 == 0ULL) ? 1 : 0;   // 1 => indices are int64
            flags[1] = (b_f32 != 0ULL) ? 1 : 0;   // 1 => floats are fp32
        }
    }
}

// ---------- merged histogram (entity heads ++ user rows), 1 elem/thread ----------
// Records {dst, rank} (normal store -> stays in L2 for the scatter's re-read).
__global__ void hist_all(const void* __restrict__ ei, const void* __restrict__ rows,
                         int* __restrict__ cnt, int2* __restrict__ dr,
                         const int* __restrict__ flags,
                         int n_edges, int nnz, int n_entities) {
    long long i = (long long)blockIdx.x * blockDim.x + threadIdx.x;
    bool i64 = flags[0] != 0;
    if (i < n_edges) {
        int dst = idx_at(ei, i, i64);
        int r = atomicAdd(&cnt[dst], 1);
        int2 p; p.x = dst; p.y = r;
        dr[i] = p;
    } else if (i < (long long)n_edges + nnz) {
        int dst = n_entities + idx_at(rows, i - n_edges, i64);
        int r = atomicAdd(&cnt[dst], 1);
        int2 p; p.x = dst; p.y = r;
        dr[i] = p;
    }
}

// ---------- hierarchical exclusive scan (3 phases, 256-wide tiles) ----------
__device__ __forceinline__ int block_scan_excl_256(int v, int* total) {
    __shared__ int tmp[256];
    int tid = threadIdx.x;
    tmp[tid] = v;
    __syncthreads();
    #pragma unroll
    for (int ofs = 1; ofs < 256; ofs <<= 1) {
        int t = (tid >= ofs) ? tmp[tid - ofs] : 0;
        __syncthreads();
        tmp[tid] += t;
        __syncthreads();
    }
    int incl = tmp[tid];
    *total = tmp[255];
    __syncthreads();                           // safe for reuse
    return incl - v;
}

__global__ void scan_p1(const int* __restrict__ cnt, int* __restrict__ bsums, int n) {
    int i = blockIdx.x * 256 + threadIdx.x;
    int v = (i < n) ? cnt[i] : 0;
    int total;
    block_scan_excl_256(v, &total);
    if (threadIdx.x == 0) bsums[blockIdx.x] = total;
}

__global__ void scan_p2(int* __restrict__ bsums, int nb) {
    int tid = threadIdx.x;
    int chunk = (nb + 255) / 256;
    int beg = tid * chunk;
    int end = min(beg + chunk, nb);
    int s = 0;
    for (int i = beg; i < end; ++i) s += bsums[i];
    int total;
    int run = block_scan_excl_256(s, &total);
    for (int i = beg; i < end; ++i) {
        int c = bsums[i];
        bsums[i] = run;
        run += c;
    }
}

__global__ void scan_p3(int* __restrict__ cnt, const int* __restrict__ bsums,
                        int* __restrict__ off, int n) {
    int i = blockIdx.x * 256 + threadIdx.x;
    int v = (i < n) ? cnt[i] : 0;
    int total;
    int excl = block_scan_excl_256(v, &total);
    int base = bsums[blockIdx.x];
    if (i < n) {
        off[i] = base + excl;
        cnt[i] = 0;                            // reset -> reuse as scatter cursor (fallback path)
        if (i == n - 1) off[n] = base + excl + v;
    }
}

// ---------- rank-based scatter: no atomics, 1 elem/thread ----------
__global__ void scatter_rank(const void* __restrict__ ei, const void* __restrict__ et,
                             const void* __restrict__ cols, const void* __restrict__ vals,
                             const int* __restrict__ off, const int2* __restrict__ dr,
                             int2* __restrict__ pairs, const int* __restrict__ flags,
                             int n_edges, int nnz) {
    long long i = (long long)blockIdx.x * blockDim.x + threadIdx.x;
    bool i64 = flags[0] != 0;
    if (i < n_edges) {
        int2 d = dr[i];
        int tail = idx_at(ei, (long long)n_edges + i, i64);
        int rel  = idx_at(et, i, i64) - 1;
        int2 p; p.x = tail; p.y = rel;
        pairs[off[d.x] + d.y] = p;
    } else if (i < (long long)n_edges + nnz) {
        long long k = i - n_edges;
        bool f32 = flags[1] != 0;
        int2 d = dr[i];
        int c = idx_at(cols, k, i64);
        float v = f32 ? ((const float*)vals)[k] : bf2f(((const unsigned short*)vals)[k]);
        int2 p; p.x = c; p.y = __float_as_int(v);
        pairs[off[d.x] + d.y] = p;
    }
}

// ---------- fallback scatter with atomic cursors (ws too small for dr) ----------
__global__ void scatter_all(const void* __restrict__ ei, const void* __restrict__ et,
                            const void* __restrict__ rows, const void* __restrict__ cols,
                            const void* __restrict__ vals,
                            const int* __restrict__ off, int* __restrict__ cur,
                            int2* __restrict__ pairs, const int* __restrict__ flags,
                            int n_edges, int nnz, int n_entities) {
    long long i = (long long)blockIdx.x * blockDim.x + threadIdx.x;
    bool i64 = flags[0] != 0;
    if (i < n_edges) {
        int head = idx_at(ei, i, i64);
        int tail = idx_at(ei, (long long)n_edges + i, i64);
        int rel  = idx_at(et, i, i64) - 1;
        int pos = off[head] + atomicAdd(&cur[head], 1);
        int2 p; p.x = tail; p.y = rel;
        pairs[pos] = p;
    } else if (i < (long long)n_edges + nnz) {
        long long k = i - n_edges;
        bool f32 = flags[1] != 0;
        int rr = n_entities + idx_at(rows, k, i64);
        int c = idx_at(cols, k, i64);
        float v = f32 ? ((const float*)vals)[k] : bf2f(((const unsigned short*)vals)[k]);
        int pos = off[rr] + atomicAdd(&cur[rr], 1);
        int2 p; p.x = c; p.y = __float_as_int(v);
        pairs[pos] = p;
    }
}

// ---------- unpack 8 bf16 (uint4) -> 8 floats ----------
__device__ __forceinline__ void unpack8(uint4 q, float* e) {
    e[0] = bf2f((unsigned short)(q.x & 0xFFFFu)); e[1] = bf2f((unsigned short)(q.x >> 16));
    e[2] = bf2f((unsigned short)(q.y & 0xFFFFu)); e[3] = bf2f((unsigned short)(q.y >> 16));
    e[4] = bf2f((unsigned short)(q.z & 0xFFFFu)); e[5] = bf2f((unsigned short)(q.z >> 16));
    e[6] = bf2f((unsigned short)(q.w & 0xFFFFu)); e[7] = bf2f((unsigned short)(q.w >> 16));
}

// ---------- merged aggregate: one 16-LANE GROUP per output row ----------
// 16 lanes x 32B cover a full fp32 row (x16B for bf16): no cross-group
// reduce. 4 independent rows per wave overlap their memory chains; a
// persistent grid-stride loop amortizes wave cold-start. Pairs are
// prefetched 16-at-a-time with one coalesced 128B load + shfl(width=16),
// so per-row latency = off -> pairs -> all-gathers-in-flight.
__global__ void agg_all(const void* __restrict__ emb, const void* __restrict__ weight,
                        const int* __restrict__ off, const int2* __restrict__ pairs,
                        void* __restrict__ out, const int* __restrict__ flags,
                        int n_entities, int n_total) {
    int tid = blockIdx.x * blockDim.x + threadIdx.x;
    int lane = threadIdx.x & 63;
    int m = lane & 15;                          // position within 16-lane group
    int g = lane >> 4;                          // group 0..3
    int gwave = tid >> 6;                       // global wave id
    int stride = (gridDim.x * blockDim.x) >> 4; // total groups in grid
    bool f32 = flags[1] != 0;

    if (f32) {
        const float4* embq = (const float4*)emb;        // 32 float4 per row
        const float4* wq   = (const float4*)weight;
        for (int row = gwave * 4 + g; row < n_total; row += stride) {
            bool isU = (row >= n_entities);
            int beg = off[row], end = off[row + 1];
            float acc[8];
            #pragma unroll
            for (int i = 0; i < 8; ++i) acc[i] = 0.f;

            for (int base = beg; base < end; base += 16) {
                int nn = min(16, end - base);
                int px = 0, py = 0;
                if (m < nn) {
                    v2i t = __builtin_nontemporal_load((const v2i*)pairs + base + m);
                    px = t.x; py = t.y;
                }
                if (isU) {
                    for (int t = 0; t < nn; ++t) {
                        int sx = __shfl(px, t, 16);
                        float v = __int_as_float(__shfl(py, t, 16));
                        const float4* rp = embq + (size_t)sx * 32 + m * 2;
                        float4 a = rp[0], b = rp[1];
                        acc[0] += v * a.x; acc[1] += v * a.y; acc[2] += v * a.z; acc[3] += v * a.w;
                        acc[4] += v * b.x; acc[5] += v * b.y; acc[6] += v * b.z; acc[7] += v * b.w;
                    }
                } else {
                    for (int t = 0; t < nn; ++t) {
                        int sx = __shfl(px, t, 16);
                        int sy = __shfl(py, t, 16);
                        const float4* rp = embq + (size_t)sx * 32 + m * 2;
                        const float4* wp = wq   + (size_t)sy * 32 + m * 2;
                        float4 a = rp[0], b = rp[1], wa = wp[0], wb = wp[1];
                        acc[0] += a.x * wa.x; acc[1] += a.y * wa.y; acc[2] += a.z * wa.z; acc[3] += a.w * wa.w;
                        acc[4] += b.x * wb.x; acc[5] += b.y * wb.y; acc[6] += b.z * wb.z; acc[7] += b.w * wb.w;
                    }
                }
            }

            if (!isU) {
                float rcp = 1.0f / fmaxf((float)(end - beg), 1.0f);
                #pragma unroll
                for (int i = 0; i < 8; ++i) acc[i] *= rcp;
            }

            v4i* rp = (v4i*)((float*)out + (size_t)row * D);
            v4i a, b;
            a.x = __float_as_int(acc[0]); a.y = __float_as_int(acc[1]);
            a.z = __float_as_int(acc[2]); a.w = __float_as_int(acc[3]);
            b.x = __float_as_int(acc[4]); b.y = __float_as_int(acc[5]);
            b.z = __float_as_int(acc[6]); b.w = __float_as_int(acc[7]);
            __builtin_nontemporal_store(a, rp + m * 2);
            __builtin_nontemporal_store(b, rp + m * 2 + 1);
        }
    } else {
        const uint4* embq = (const uint4*)emb;          // 16 uint4 per row
        const uint4* wq   = (const uint4*)weight;
        for (int row = gwave * 4 + g; row < n_total; row += stride) {
            bool isU = (row >= n_entities);
            int beg = off[row], end = off[row + 1];
            float acc[8];
            #pragma unroll
            for (int i = 0; i < 8; ++i) acc[i] = 0.f;

            for (int base = beg; base < end; base += 16) {
                int nn = min(16, end - base);
                int px = 0, py = 0;
                if (m < nn) {
                    v2i t = __builtin_nontemporal_load((const v2i*)pairs + base + m);
                    px = t.x; py = t.y;
                }
                if (isU) {
                    for (int t = 0; t < nn; ++t) {
                        int sx = __shfl(px, t, 16);
                        float v = __int_as_float(__shfl(py, t, 16));
                        uint4 q = embq[(size_t)sx * 16 + m];
                        float e[8]; unpack8(q, e);
                        #pragma unroll
                        for (int i = 0; i < 8; ++i) acc[i] += v * e[i];
                    }
                } else {
                    for (int t = 0; t < nn; ++t) {
                        int sx = __shfl(px, t, 16);
                        int sy = __shfl(py, t, 16);
                        uint4 q  = embq[(size_t)sx * 16 + m];
                        uint4 qw = wq[(size_t)sy * 16 + m];
                        float e[8], wv[8]; unpack8(q, e); unpack8(qw, wv);
                        #pragma unroll
                        for (int i = 0; i < 8; ++i) acc[i] += e[i] * wv[i];
                    }
                }
            }

            if (!isU) {
                float rcp = 1.0f / fmaxf((float)(end - beg), 1.0f);
                #pragma unroll
                for (int i = 0; i < 8; ++i) acc[i] *= rcp;
            }

            v4i o;
            o.x = (int)((unsigned int)f2bf(acc[0]) | ((unsigned int)f2bf(acc[1]) << 16));
            o.y = (int)((unsigned int)f2bf(acc[2]) | ((unsigned int)f2bf(acc[3]) << 16));
            o.z = (int)((unsigned int)f2bf(acc[4]) | ((unsigned int)f2bf(acc[5]) << 16));
            o.w = (int)((unsigned int)f2bf(acc[6]) | ((unsigned int)f2bf(acc[7]) << 16));
            __builtin_nontemporal_store(o, (v4i*)out + (size_t)row * 8 + m);
        }
    }
}

extern "C" void kernel_launch(void* const* d_in, const int* in_sizes, int n_in,
                              void* d_out, int out_size, void* d_ws, size_t ws_size,
                              hipStream_t stream) {
    const void* emb  = d_in[0];   // [n_entities][D] bf16 or fp32
    const void* ei   = d_in[1];   // [2][n_edges]    int32 or int64
    const void* et   = d_in[2];   // [n_edges]
    const void* rows = d_in[3];   // [nnz]
    const void* cols = d_in[4];   // [nnz]
    const void* vals = d_in[5];   // [nnz] bf16 or fp32

    // weight = last input with >=256 elements (robust to scalar presence)
    const void* weight = d_in[n_in - 1];
    for (int i = n_in - 1; i >= 5; --i) {
        if (in_sizes[i] >= 256) { weight = d_in[i]; break; }
    }

    int n_entities = in_sizes[0] / D;
    int n_edges    = in_sizes[2];
    int nnz        = in_sizes[5];
    int n_users    = out_size / D - n_entities;

    int n_concat = n_entities + n_users;       // concatenated row space
    int nb = (n_concat + 255) / 256;           // scan tiles
    long long n_pairs = (long long)n_edges + nnz;

    // ws layout:
    //   [pairs: n_pairs int2][dr: n_pairs int2 (optional)][off: n_concat+1]
    //   [cnt: n_concat][bsums: nb][flags: 2]
    size_t fixed = (size_t)(n_concat + 1 + n_concat + nb + 2) * sizeof(int);
    bool use_rank = ws_size >= (size_t)n_pairs * sizeof(int2) * 2 + fixed + 256;

    char* p = (char*)d_ws;
    int2* pairs = (int2*)p;                      p += (size_t)n_pairs * sizeof(int2);
    int2* dr = nullptr;
    if (use_rank) { dr = (int2*)p;               p += (size_t)n_pairs * sizeof(int2); }
    int*  off   = (int*)p;                       p += (size_t)(n_concat + 1) * sizeof(int);
    int*  cnt   = (int*)p;                       p += (size_t)n_concat * sizeof(int);
    int*  bsums = (int*)p;                       p += (size_t)nb * sizeof(int);
    int*  flags = (int*)p;

    const int tpb = 256;

    // init: zero cnt + dtype probes (replaces memset + detect dispatches)
    init_all<<<nb, tpb, 0, stream>>>(cnt, n_concat, (const int*)et,
                                     (const unsigned short*)emb, flags);

    // merged histogram (+ rank record when workspace permits)
    hist_all<<<(int)((n_pairs + tpb - 1) / tpb), tpb, 0, stream>>>(
        ei, rows, cnt, dr, flags, n_edges, nnz, n_entities);

    // hierarchical exclusive scan (also zeroes cnt for cursor fallback)
    scan_p1<<<nb, 256, 0, stream>>>(cnt, bsums, n_concat);
    scan_p2<<<1, 256, 0, stream>>>(bsums, nb);
    scan_p3<<<nb, 256, 0, stream>>>(cnt, bsums, off, n_concat);

    // scatter: atomic-free when ranks were recorded
    if (use_rank) {
        scatter_rank<<<(int)((n_pairs + tpb - 1) / tpb), tpb, 0, stream>>>(
            ei, et, cols, vals, off, dr, pairs, flags, n_edges, nnz);
    } else {
        scatter_all<<<(int)((n_pairs + tpb - 1) / tpb), tpb, 0, stream>>>(
            ei, et, rows, cols, vals, off, cnt, pairs, flags, n_edges, nnz, n_entities);
    }

    // merged gather-aggregate: persistent grid, one 16-lane group per row
    {
        int blocks_needed = (n_concat + 15) / 16;   // 16 rows per 256-thread block
        int blocks = min(2048, blocks_needed);      // 256 CU x 8 blocks persistent
        agg_all<<<blocks, tpb, 0, stream>>>(
            emb, weight, off, pairs, d_out, flags, n_entities, n_concat);
    }
}

// Round 5
// 351.074 us; speedup vs baseline: 1.0405x; 1.0072x over previous
//
#include <hip/hip_runtime.h>

#define D 128

typedef int v2i __attribute__((ext_vector_type(2)));
typedef int v4i __attribute__((ext_vector_type(4)));

// ---------- bf16 helpers (raw ushort representation) ----------
__device__ __forceinline__ float bf2f(unsigned short u) {
    union { unsigned int i; float f; } v;
    v.i = ((unsigned int)u) << 16;
    return v.f;
}
__device__ __forceinline__ unsigned short f2bf(float f) {
    union { float f; unsigned int i; } v;
    v.f = f;
    unsigned int x = v.i;
    unsigned int round_bit = (x >> 16) & 1u;   // round-to-nearest-even
    x += 0x7fffu + round_bit;
    return (unsigned short)(x >> 16);
}

__device__ __forceinline__ int idx_at(const void* p, long long i, bool i64) {
    return i64 ? (int)((const long long*)p)[i] : ((const int*)p)[i];
}

// ---------- init: zero cnt (grid-stride) + layout probe flags (block 0) ----------
__global__ void init_all(int* __restrict__ cnt, int n_concat,
                         const int* __restrict__ et_i32,
                         const unsigned short* __restrict__ emb_u16,
                         int* __restrict__ flags) {
    int i = blockIdx.x * blockDim.x + threadIdx.x;
    for (; i < n_concat; i += gridDim.x * blockDim.x) cnt[i] = 0;

    if (blockIdx.x == 0 && threadIdx.x < 64) {
        int lane = threadIdx.x;                // 0..63
        int v = et_i32[2 * lane + 1];
        unsigned long long b_i64 = __ballot(v != 0);

        unsigned short a = emb_u16[2 * lane];
        unsigned short c = emb_u16[2 * lane + 1];
        int e1 = (a >> 7) & 0xFF;
        int e2 = (c >> 7) & 0xFF;
        unsigned long long b_f32 = __ballot(e1 > 140 || e2 > 140);

        if (lane == 0) {
            flags[0] = (b_i64 == 0ULL) ? 1 : 0;   // 1 => indices are int64
            flags[1] = (b_f32 != 0ULL) ? 1 : 0;   // 1 => floats are fp32
        }
    }
}

// ---------- merged histogram (entity heads ++ user rows) ----------
// Records {dst, rank} (normal store -> stays in L2 for the scatter's re-read).
__global__ void hist_all(const void* __restrict__ ei, const void* __restrict__ rows,
                         int* __restrict__ cnt, int2* __restrict__ dr,
                         const int* __restrict__ flags,
                         int n_edges, int nnz, int n_entities) {
    long long i = (long long)blockIdx.x * blockDim.x + threadIdx.x;
    bool i64 = flags[0] != 0;
    if (i < n_edges) {
        int dst = idx_at(ei, i, i64);
        int r = atomicAdd(&cnt[dst], 1);
        int2 p; p.x = dst; p.y = r;
        dr[i] = p;
    } else if (i < (long long)n_edges + nnz) {
        int dst = n_entities + idx_at(rows, i - n_edges, i64);
        int r = atomicAdd(&cnt[dst], 1);
        int2 p; p.x = dst; p.y = r;
        dr[i] = p;
    }
}

// ---------- hierarchical exclusive scan (3 phases, 256-wide tiles) ----------
__device__ __forceinline__ int block_scan_excl_256(int v, int* total) {
    __shared__ int tmp[256];
    int tid = threadIdx.x;
    tmp[tid] = v;
    __syncthreads();
    #pragma unroll
    for (int ofs = 1; ofs < 256; ofs <<= 1) {
        int t = (tid >= ofs) ? tmp[tid - ofs] : 0;
        __syncthreads();
        tmp[tid] += t;
        __syncthreads();
    }
    int incl = tmp[tid];
    *total = tmp[255];
    __syncthreads();                           // safe for reuse
    return incl - v;
}

__global__ void scan_p1(const int* __restrict__ cnt, int* __restrict__ bsums, int n) {
    int i = blockIdx.x * 256 + threadIdx.x;
    int v = (i < n) ? cnt[i] : 0;
    int total;
    block_scan_excl_256(v, &total);
    if (threadIdx.x == 0) bsums[blockIdx.x] = total;
}

__global__ void scan_p2(int* __restrict__ bsums, int nb) {
    int tid = threadIdx.x;
    int chunk = (nb + 255) / 256;
    int beg = tid * chunk;
    int end = min(beg + chunk, nb);
    int s = 0;
    for (int i = beg; i < end; ++i) s += bsums[i];
    int total;
    int run = block_scan_excl_256(s, &total);
    for (int i = beg; i < end; ++i) {
        int c = bsums[i];
        bsums[i] = run;
        run += c;
    }
}

__global__ void scan_p3(int* __restrict__ cnt, const int* __restrict__ bsums,
                        int* __restrict__ off, int n) {
    int i = blockIdx.x * 256 + threadIdx.x;
    int v = (i < n) ? cnt[i] : 0;
    int total;
    int excl = block_scan_excl_256(v, &total);
    int base = bsums[blockIdx.x];
    if (i < n) {
        off[i] = base + excl;
        cnt[i] = 0;                            // reset -> reuse as scatter cursor (fallback path)
        if (i == n - 1) off[n] = base + excl + v;
    }
}

// ---------- rank-based scatter: no atomics ----------
__global__ void scatter_rank(const void* __restrict__ ei, const void* __restrict__ et,
                             const void* __restrict__ cols, const void* __restrict__ vals,
                             const int* __restrict__ off, const int2* __restrict__ dr,
                             int2* __restrict__ pairs, const int* __restrict__ flags,
                             int n_edges, int nnz) {
    long long i = (long long)blockIdx.x * blockDim.x + threadIdx.x;
    bool i64 = flags[0] != 0;
    if (i < n_edges) {
        int2 d = dr[i];
        int tail = idx_at(ei, (long long)n_edges + i, i64);
        int rel  = idx_at(et, i, i64) - 1;
        int2 p; p.x = tail; p.y = rel;
        pairs[off[d.x] + d.y] = p;
    } else if (i < (long long)n_edges + nnz) {
        long long k = i - n_edges;
        bool f32 = flags[1] != 0;
        int2 d = dr[i];
        int c = idx_at(cols, k, i64);
        float v = f32 ? ((const float*)vals)[k] : bf2f(((const unsigned short*)vals)[k]);
        int2 p; p.x = c; p.y = __float_as_int(v);
        pairs[off[d.x] + d.y] = p;
    }
}

// ---------- fallback scatter with atomic cursors (ws too small for dr) ----------
__global__ void scatter_all(const void* __restrict__ ei, const void* __restrict__ et,
                            const void* __restrict__ rows, const void* __restrict__ cols,
                            const void* __restrict__ vals,
                            const int* __restrict__ off, int* __restrict__ cur,
                            int2* __restrict__ pairs, const int* __restrict__ flags,
                            int n_edges, int nnz, int n_entities) {
    long long i = (long long)blockIdx.x * blockDim.x + threadIdx.x;
    bool i64 = flags[0] != 0;
    if (i < n_edges) {
        int head = idx_at(ei, i, i64);
        int tail = idx_at(ei, (long long)n_edges + i, i64);
        int rel  = idx_at(et, i, i64) - 1;
        int pos = off[head] + atomicAdd(&cur[head], 1);
        int2 p; p.x = tail; p.y = rel;
        pairs[pos] = p;
    } else if (i < (long long)n_edges + nnz) {
        long long k = i - n_edges;
        bool f32 = flags[1] != 0;
        int rr = n_entities + idx_at(rows, k, i64);
        int c = idx_at(cols, k, i64);
        float v = f32 ? ((const float*)vals)[k] : bf2f(((const unsigned short*)vals)[k]);
        int pos = off[rr] + atomicAdd(&cur[rr], 1);
        int2 p; p.x = c; p.y = __float_as_int(v);
        pairs[pos] = p;
    }
}

// ---------- unpack bf16 ----------
__device__ __forceinline__ void unpack4(uint2 q, float* e) {
    e[0] = bf2f((unsigned short)(q.x & 0xFFFFu)); e[1] = bf2f((unsigned short)(q.x >> 16));
    e[2] = bf2f((unsigned short)(q.y & 0xFFFFu)); e[3] = bf2f((unsigned short)(q.y >> 16));
}

// ================= aggregate: one 32-LANE GROUP per output row =================
// fp32: lane m owns float4 index m of the 512B row -> ONE dwordx4 per pair
// per lane. Explicit 4-deep unrolled load batch => ~8 independent row
// gathers in flight per wave (2 groups x 4). Persistent grid-stride.
__global__ void agg_all(const void* __restrict__ emb, const void* __restrict__ weight,
                        const int* __restrict__ off, const int2* __restrict__ pairs,
                        void* __restrict__ out, const int* __restrict__ flags,
                        int n_entities, int n_total) {
    int tid = blockIdx.x * blockDim.x + threadIdx.x;
    int m = threadIdx.x & 31;                    // lane within 32-lane group
    int grp = tid >> 5;                          // global group id
    int stride = (gridDim.x * blockDim.x) >> 5;  // total groups
    bool f32 = flags[1] != 0;

    if (f32) {
        const float4* embq = (const float4*)emb;        // 32 float4 per row
        const float4* wq   = (const float4*)weight;
        for (int row = grp; row < n_total; row += stride) {
            bool isU = (row >= n_entities);
            int beg = off[row], end = off[row + 1];
            float4 acc; acc.x = acc.y = acc.z = acc.w = 0.f;

            for (int base = beg; base < end; base += 32) {
                int nn = min(32, end - base);
                int px = 0, py = 0;
                if (m < nn) {
                    v2i t = __builtin_nontemporal_load((const v2i*)pairs + base + m);
                    px = t.x; py = t.y;
                }
                int t = 0;
                if (isU) {
                    for (; t + 4 <= nn; t += 4) {
                        int sx0 = __shfl(px, t, 32),     sx1 = __shfl(px, t + 1, 32);
                        int sx2 = __shfl(px, t + 2, 32), sx3 = __shfl(px, t + 3, 32);
                        float v0 = __int_as_float(__shfl(py, t, 32));
                        float v1 = __int_as_float(__shfl(py, t + 1, 32));
                        float v2 = __int_as_float(__shfl(py, t + 2, 32));
                        float v3 = __int_as_float(__shfl(py, t + 3, 32));
                        float4 a0 = embq[(size_t)sx0 * 32 + m];
                        float4 a1 = embq[(size_t)sx1 * 32 + m];
                        float4 a2 = embq[(size_t)sx2 * 32 + m];
                        float4 a3 = embq[(size_t)sx3 * 32 + m];
                        acc.x += v0 * a0.x + v1 * a1.x + v2 * a2.x + v3 * a3.x;
                        acc.y += v0 * a0.y + v1 * a1.y + v2 * a2.y + v3 * a3.y;
                        acc.z += v0 * a0.z + v1 * a1.z + v2 * a2.z + v3 * a3.z;
                        acc.w += v0 * a0.w + v1 * a1.w + v2 * a2.w + v3 * a3.w;
                    }
                    for (; t < nn; ++t) {
                        int sx = __shfl(px, t, 32);
                        float v = __int_as_float(__shfl(py, t, 32));
                        float4 a = embq[(size_t)sx * 32 + m];
                        acc.x += v * a.x; acc.y += v * a.y; acc.z += v * a.z; acc.w += v * a.w;
                    }
                } else {
                    for (; t + 4 <= nn; t += 4) {
                        int sx0 = __shfl(px, t, 32),     sx1 = __shfl(px, t + 1, 32);
                        int sx2 = __shfl(px, t + 2, 32), sx3 = __shfl(px, t + 3, 32);
                        int sy0 = __shfl(py, t, 32),     sy1 = __shfl(py, t + 1, 32);
                        int sy2 = __shfl(py, t + 2, 32), sy3 = __shfl(py, t + 3, 32);
                        float4 a0 = embq[(size_t)sx0 * 32 + m];
                        float4 a1 = embq[(size_t)sx1 * 32 + m];
                        float4 a2 = embq[(size_t)sx2 * 32 + m];
                        float4 a3 = embq[(size_t)sx3 * 32 + m];
                        float4 w0 = wq[(size_t)sy0 * 32 + m];
                        float4 w1 = wq[(size_t)sy1 * 32 + m];
                        float4 w2 = wq[(size_t)sy2 * 32 + m];
                        float4 w3 = wq[(size_t)sy3 * 32 + m];
                        acc.x += a0.x * w0.x + a1.x * w1.x + a2.x * w2.x + a3.x * w3.x;
                        acc.y += a0.y * w0.y + a1.y * w1.y + a2.y * w2.y + a3.y * w3.y;
                        acc.z += a0.z * w0.z + a1.z * w1.z + a2.z * w2.z + a3.z * w3.z;
                        acc.w += a0.w * w0.w + a1.w * w1.w + a2.w * w2.w + a3.w * w3.w;
                    }
                    for (; t < nn; ++t) {
                        int sx = __shfl(px, t, 32);
                        int sy = __shfl(py, t, 32);
                        float4 a = embq[(size_t)sx * 32 + m];
                        float4 w = wq[(size_t)sy * 32 + m];
                        acc.x += a.x * w.x; acc.y += a.y * w.y; acc.z += a.z * w.z; acc.w += a.w * w.w;
                    }
                }
            }

            if (!isU) {
                float rcp = 1.0f / fmaxf((float)(end - beg), 1.0f);
                acc.x *= rcp; acc.y *= rcp; acc.z *= rcp; acc.w *= rcp;
            }

            v4i o;
            o.x = __float_as_int(acc.x); o.y = __float_as_int(acc.y);
            o.z = __float_as_int(acc.z); o.w = __float_as_int(acc.w);
            __builtin_nontemporal_store(o, (v4i*)out + (size_t)row * 32 + m);
        }
    } else {
        const uint2* embh = (const uint2*)emb;          // 32 uint2 per 256B row
        const uint2* wh   = (const uint2*)weight;
        for (int row = grp; row < n_total; row += stride) {
            bool isU = (row >= n_entities);
            int beg = off[row], end = off[row + 1];
            float acc[4] = {0.f, 0.f, 0.f, 0.f};

            for (int base = beg; base < end; base += 32) {
                int nn = min(32, end - base);
                int px = 0, py = 0;
                if (m < nn) {
                    v2i t = __builtin_nontemporal_load((const v2i*)pairs + base + m);
                    px = t.x; py = t.y;
                }
                for (int t = 0; t < nn; ++t) {
                    int sx = __shfl(px, t, 32);
                    if (isU) {
                        float v = __int_as_float(__shfl(py, t, 32));
                        uint2 q = embh[(size_t)sx * 32 + m];
                        float e[4]; unpack4(q, e);
                        #pragma unroll
                        for (int i = 0; i < 4; ++i) acc[i] += v * e[i];
                    } else {
                        int sy = __shfl(py, t, 32);
                        uint2 q  = embh[(size_t)sx * 32 + m];
                        uint2 qw = wh[(size_t)sy * 32 + m];
                        float e[4], wv[4]; unpack4(q, e); unpack4(qw, wv);
                        #pragma unroll
                        for (int i = 0; i < 4; ++i) acc[i] += e[i] * wv[i];
                    }
                }
            }

            if (!isU) {
                float rcp = 1.0f / fmaxf((float)(end - beg), 1.0f);
                #pragma unroll
                for (int i = 0; i < 4; ++i) acc[i] *= rcp;
            }

            v2i o;
            o.x = (int)((unsigned int)f2bf(acc[0]) | ((unsigned int)f2bf(acc[1]) << 16));
            o.y = (int)((unsigned int)f2bf(acc[2]) | ((unsigned int)f2bf(acc[3]) << 16));
            __builtin_nontemporal_store(o, (v2i*)out + (size_t)row * 32 + m);
        }
    }
}

extern "C" void kernel_launch(void* const* d_in, const int* in_sizes, int n_in,
                              void* d_out, int out_size, void* d_ws, size_t ws_size,
                              hipStream_t stream) {
    const void* emb  = d_in[0];   // [n_entities][D] bf16 or fp32
    const void* ei   = d_in[1];   // [2][n_edges]    int32 or int64
    const void* et   = d_in[2];   // [n_edges]
    const void* rows = d_in[3];   // [nnz]
    const void* cols = d_in[4];   // [nnz]
    const void* vals = d_in[5];   // [nnz] bf16 or fp32

    // weight = last input with >=256 elements (robust to scalar presence)
    const void* weight = d_in[n_in - 1];
    for (int i = n_in - 1; i >= 5; --i) {
        if (in_sizes[i] >= 256) { weight = d_in[i]; break; }
    }

    int n_entities = in_sizes[0] / D;
    int n_edges    = in_sizes[2];
    int nnz        = in_sizes[5];
    int n_users    = out_size / D - n_entities;

    int n_concat = n_entities + n_users;       // concatenated row space
    int nb = (n_concat + 255) / 256;           // scan tiles
    long long n_pairs = (long long)n_edges + nnz;

    // ws layout:
    //   [pairs: n_pairs int2][dr: n_pairs int2 (optional)][off: n_concat+1]
    //   [cnt: n_concat][bsums: nb][flags: 2]
    size_t fixed = (size_t)(n_concat + 1 + n_concat + nb + 2) * sizeof(int);
    bool use_rank = ws_size >= (size_t)n_pairs * sizeof(int2) * 2 + fixed + 256;

    char* p = (char*)d_ws;
    int2* pairs = (int2*)p;                      p += (size_t)n_pairs * sizeof(int2);
    int2* dr = nullptr;
    if (use_rank) { dr = (int2*)p;               p += (size_t)n_pairs * sizeof(int2); }
    int*  off   = (int*)p;                       p += (size_t)(n_concat + 1) * sizeof(int);
    int*  cnt   = (int*)p;                       p += (size_t)n_concat * sizeof(int);
    int*  bsums = (int*)p;                       p += (size_t)nb * sizeof(int);
    int*  flags = (int*)p;

    const int tpb = 256;

    // init: zero cnt + dtype probes
    init_all<<<nb, tpb, 0, stream>>>(cnt, n_concat, (const int*)et,
                                     (const unsigned short*)emb, flags);

    // merged histogram (+ rank record when workspace permits)
    hist_all<<<(int)((n_pairs + tpb - 1) / tpb), tpb, 0, stream>>>(
        ei, rows, cnt, dr ? dr : pairs /*unused if !use_rank*/, flags,
        n_edges, nnz, n_entities);

    // hierarchical exclusive scan (also zeroes cnt for cursor fallback)
    scan_p1<<<nb, 256, 0, stream>>>(cnt, bsums, n_concat);
    scan_p2<<<1, 256, 0, stream>>>(bsums, nb);
    scan_p3<<<nb, 256, 0, stream>>>(cnt, bsums, off, n_concat);

    // scatter: atomic-free when ranks were recorded
    if (use_rank) {
        scatter_rank<<<(int)((n_pairs + tpb - 1) / tpb), tpb, 0, stream>>>(
            ei, et, cols, vals, off, dr, pairs, flags, n_edges, nnz);
    } else {
        scatter_all<<<(int)((n_pairs + tpb - 1) / tpb), tpb, 0, stream>>>(
            ei, et, rows, cols, vals, off, cnt, pairs, flags, n_edges, nnz, n_entities);
    }

    // aggregate: persistent grid, one 32-lane group per row
    {
        int blocks_needed = (n_concat + 7) / 8;     // 8 rows per 256-thread block pass
        int blocks = blocks_needed < 2048 ? blocks_needed : 2048;
        agg_all<<<blocks, tpb, 0, stream>>>(
            emb, weight, off, pairs, d_out, flags, n_entities, n_concat);
    }
}